// Round 11
// baseline (248.992 us; speedup 1.0000x reference)
//
#include <hip/hip_runtime.h>

typedef __attribute__((ext_vector_type(8))) short short8;
typedef __attribute__((ext_vector_type(4))) float float4v;
typedef __attribute__((ext_vector_type(4))) int int4v;
typedef __attribute__((ext_vector_type(2))) int int2v;

#define E_EDGES 300000
#define EPB 256                                 // edges per block (32 per wave, 8 waves)
#define NBLK ((E_EDGES + EPB - 1) / EPB)        // 1172 blocks per edge type
#define TAB_ELEMS 12800000                      // 100000 nodes x 128 feats

__device__ __forceinline__ short f2bf(float f) {
    unsigned u = __float_as_uint(f);
    return (short)((u + 0x7FFFu + ((u >> 16) & 1u)) >> 16);
}
__device__ __forceinline__ unsigned pk_bf16(float a, float b) {
    unsigned ua = __float_as_uint(a), ub = __float_as_uint(b);
    ua += 0x7FFFu + ((ua >> 16) & 1u);
    ub += 0x7FFFu + ((ub >> 16) & 1u);
    return __builtin_amdgcn_perm(ub, ua, 0x07060302);
}
// HW RNE pack of two f32 -> one u32 of 2 bf16 (lo = a, hi = b).
__device__ __forceinline__ unsigned cvtpk(float a, float b) {
    unsigned r;
    __asm__("v_cvt_pk_bf16_f32 %0, %1, %2" : "=v"(r) : "v"(a), "v"(b));
    return r;
}
__device__ __forceinline__ void cp16(const void* g, void* l) {
    __builtin_amdgcn_global_load_lds(
        (const __attribute__((address_space(1))) unsigned int*)g,
        (__attribute__((address_space(3))) unsigned int*)l, 16, 0, 0);
}

// Counted-vmcnt barrier (T4): waits only until <=N VMEM loads outstanding,
// so the freshest N loads (gather prefetches) stay in flight ACROSS the
// barrier instead of being drained by __syncthreads' vmcnt(0).
// "memory" clobber pins all memory-op ordering across it. Over-waiting
// (N smaller than loads-issued-since-the-guarded-cp16) is always safe.
#define CBAR(N) asm volatile("s_waitcnt vmcnt(" #N ")\n\ts_barrier" ::: "memory")

// ws layout (shorts):
//   [0..98304)            weight tiles [n][k] in 64-k tiles, chunk-XOR swizzled
//   [98304..+12.8M)       user_emb bf16
//   [..+25.6M)            item_emb bf16
__global__ void prep_all(const float* __restrict__ ue, const float* __restrict__ ie,
                         const float* __restrict__ Wbi_ui, const float* __restrict__ W1_ui,
                         const float* __restrict__ Wbi_iu, const float* __restrict__ W1_iu,
                         short* __restrict__ ws) {
    __shared__ short tr[64 * 68];
    const int t = blockIdx.y;
    const int tid = threadIdx.x;
    if (blockIdx.x < 1024) {                    // ---- streaming table conversion ----
        const float* src = t ? ie : ue;
        short* dst = ws + 98304 + (size_t)t * TAB_ELEMS;
        const int stride = 1024 * 256;
        for (int g = blockIdx.x * 256 + tid; g < TAB_ELEMS / 8; g += stride) {
            const float* p = src + (size_t)g * 8;
            float4v v0 = ((const float4v*)p)[0];
            float4v v1 = ((const float4v*)p)[1];
            int4v w = { (int)pk_bf16(v0[0], v0[1]), (int)pk_bf16(v0[2], v0[3]),
                        (int)pk_bf16(v1[0], v1[1]), (int)pk_bf16(v1[2], v1[3]) };
            *(int4v*)(dst + (size_t)g * 8) = w;
        }
        return;
    }
    // ---- weight transpose + swizzle (12 tiles per type) ----
    const int m = blockIdx.x - 1024;            // 0..11
    const float* W; int k0, n0, obase;
    if (m < 8) {                                // Wbi (K=256, N=128)
        int kt = m >> 1, nh = m & 1;
        W = t ? Wbi_iu : Wbi_ui; k0 = kt * 64; n0 = nh * 64;
        obase = t * 32768 + kt * 8192;
    } else {                                    // W1 (K=128, N=128)
        int mm = m - 8; int kt = mm >> 1, nh = mm & 1;
        W = t ? W1_iu : W1_ui; k0 = kt * 64; n0 = nh * 64;
        obase = 65536 + t * 16384 + kt * 8192;
    }
    for (int it = 0; it < 16; ++it) {
        int flat = it * 256 + tid;
        int kk = flat >> 6, nn = flat & 63;
        tr[nn * 68 + kk] = f2bf(W[(size_t)(k0 + kk) * 128 + n0 + nn]);
    }
    __syncthreads();
    for (int it = 0; it < 16; ++it) {
        int flat = it * 256 + tid;
        int nn = flat >> 6, kk = flat & 63;
        int n = n0 + nn;
        ws[obase + n * 64 + (kk ^ ((n & 7) << 3))] = tr[nn * 68 + kk];
    }
}

// Round-10 verified cell + T4 counted-vmcnt barriers on the three hot L1
// barriers: gather prefetches (the 4-8 freshest loads) stay in flight across
// each barrier instead of being drained (the m97-structure vmcnt(0) stall,
// here amplified by ~500-900cyc random-gather latency). To keep counts sound:
//  - acc ZERO-init (bias folded into epilogue adds) so no VMEM loads with
//    register-dep auto-waits sit between the gathers and barrier 1;
//  - bias/W2 loads confined to the plain-__syncthreads epilogue region.
// lgkm safety: every ds_read is consumed by an MFMA before its barrier; the
// H ds_write phase stays behind full __syncthreads.
template<bool BF16G>
__launch_bounds__(512, 4)
__global__ void edge_decoder(
    const float* __restrict__ user_emb, const float* __restrict__ item_emb,
    const int* __restrict__ ei_ui, const int* __restrict__ ei_iu,
    const float* __restrict__ b_bi_ui, const float* __restrict__ b1_ui,
    const float* __restrict__ W2_ui, const float* __restrict__ b2_ui,
    const float* __restrict__ b_bi_iu, const float* __restrict__ b1_iu,
    const float* __restrict__ W2_iu, const float* __restrict__ b2_iu,
    const short* __restrict__ ws, const short* __restrict__ tab,
    float* __restrict__ out)
{
    __shared__ short Blds[2][128 * 64];         // 32 KiB weight double buffer
    __shared__ short HL[8 * 2176];              // 34 KiB H (16 rows x 136 per wave)

    const int type = blockIdx.y;
    const int tid = threadIdx.x;
    const int wave = tid >> 6, lane = tid & 63;
    const int q = lane >> 4, ln = lane & 15;
    const int e0 = blockIdx.x * EPB;

    const int*   ei   = type ? ei_iu : ei_ui;
    const float* bbi  = type ? b_bi_iu : b_bi_ui;
    const float* b1v  = type ? b1_iu : b1_ui;
    const float* W2v  = type ? W2_iu : W2_ui;
    const float* b2v  = type ? b2_iu : b2_ui;
    const short* WbiT = ws + type * 32768;
    const short* W1T  = ws + 65536 + type * 16384;

    // DMA weight tile 0 -> buf0 immediately (oldest VMEM ops in flight)
    #pragma unroll
    for (int c = 0; c < 2; ++c)
        cp16(WbiT + c * 4096 + tid * 8, &Blds[0][c * 4096 + tid * 8]);

    // two edges per lane (M-tiles mt=0,1); edge-in-tile = ln
    int si[2], di[2];
    #pragma unroll
    for (int mt = 0; mt < 2; ++mt) {
        int erow = e0 + wave * 32 + mt * 16 + ln;
        int safe = (erow < E_EDGES) ? erow : 0;
        si[mt] = ei[safe];
        di[mt] = ei[E_EDGES + safe];
    }

    const short* sp[2]; const short* dp[2];     // bf16-table path
    const float* spf[2]; const float* dpf[2];   // fp32 fallback path
    if (BF16G) {
        #pragma unroll
        for (int mt = 0; mt < 2; ++mt) {
            sp[mt] = tab + (size_t)(type ? TAB_ELEMS : 0) + (size_t)si[mt] * 128 + q * 8;
            dp[mt] = tab + (size_t)(type ? 0 : TAB_ELEMS) + (size_t)di[mt] * 128 + q * 8;
        }
    } else {
        const float* srcT = type ? item_emb : user_emb;
        const float* dstT = type ? user_emb : item_emb;
        #pragma unroll
        for (int mt = 0; mt < 2; ++mt) {
            spf[mt] = srcT + (size_t)si[mt] * 128 + q * 8;
            dpf[mt] = dstT + (size_t)di[mt] * 128 + q * 8;
        }
    }

    short8 aA[2][2], aB[2][2];                  // ping-pong per-tile edge fragments

#define GATHER(BUF, HALF, OFF) do { \
    _Pragma("unroll") \
    for (int mt = 0; mt < 2; ++mt) { \
        _Pragma("unroll") \
        for (int k2 = 0; k2 < 2; ++k2) { \
            if (BF16G) { \
                BUF[mt][k2] = *(const short8*)((HALF ? dp[mt] : sp[mt]) + OFF + k2 * 32); \
            } else { \
                const float* p = (HALF ? dpf[mt] : spf[mt]) + OFF + k2 * 32; \
                float4v v0 = ((const float4v*)p)[0]; \
                float4v v1 = ((const float4v*)p)[1]; \
                int4v w = { (int)cvtpk(v0[0], v0[1]), (int)cvtpk(v0[2], v0[3]), \
                            (int)cvtpk(v1[0], v1[1]), (int)cvtpk(v1[2], v1[3]) }; \
                BUF[mt][k2] = *(short8*)&w; \
            } \
        } \
    } } while (0)

    GATHER(aA, 0, 0);                           // tile 0: src[0:64)
    GATHER(aB, 0, 64);                          // tile 1: src[64:128)

    // acc ZERO-init: no VMEM loads here -> no auto vmcnt(0) drain before CBAR.
    // Bias is added in the epilogues instead.
    float4v acc[2][8];
    #pragma unroll
    for (int nt = 0; nt < 8; ++nt) {
        acc[0][nt] = (float4v){0.f, 0.f, 0.f, 0.f};
        acc[1][nt] = (float4v){0.f, 0.f, 0.f, 0.f};
    }

    const int swz = (ln & 7) << 3;              // weight-tile 16B-chunk xor

// One layer-1 K-tile, SWAPPED operands: mfma(W_frag, edge_frag, acc).
// BARRIER guards "tile KT resident in buf[KT&1]" (cp16 issued last tile).
#define L1_TILE(KT, ABUF, BARRIER) do { \
    BARRIER; \
    const short* nxt = (KT < 3) ? (WbiT + (KT + 1) * 8192) : W1T; \
    _Pragma("unroll") \
    for (int c = 0; c < 2; ++c) \
        cp16(nxt + c * 4096 + tid * 8, &Blds[(KT + 1) & 1][c * 4096 + tid * 8]); \
    __builtin_amdgcn_s_setprio(1); \
    _Pragma("unroll") \
    for (int ks2 = 0; ks2 < 2; ++ks2) { \
        int ka = (ks2 * 32 + q * 8) ^ swz; \
        _Pragma("unroll") \
        for (int nt = 0; nt < 8; ++nt) { \
            short8 bf = *(const short8*)&Blds[KT & 1][(nt * 16 + ln) * 64 + ka]; \
            acc[0][nt] = __builtin_amdgcn_mfma_f32_16x16x32_bf16(bf, ABUF[0][ks2], acc[0][nt], 0, 0, 0); \
            acc[1][nt] = __builtin_amdgcn_mfma_f32_16x16x32_bf16(bf, ABUF[1][ks2], acc[1][nt], 0, 0, 0); \
        } \
    } \
    __builtin_amdgcn_s_setprio(0); \
    } while (0)

    // ---- Layer 1: K=256 concat [src|dst], 4 tiles of 64-K ----
    // Counted barriers: N = loads issued AFTER the cp16 being guarded
    // (bf16 path; fp32 path issues more -> over-wait, still safe).
    L1_TILE(0, aA, CBAR(8));                    // keeps aA+aB gathers in flight
    GATHER(aA, 1, 0);                           // tile 2: dst[0:64)
    L1_TILE(1, aB, CBAR(4));                    // keeps aA2 gathers in flight
    GATHER(aB, 1, 64);                          // tile 3: dst[64:128)
    L1_TILE(2, aA, CBAR(4));                    // keeps aB2 gathers in flight
    L1_TILE(3, aB, __syncthreads());            // full drain; stages W1t0 -> buf0

    __syncthreads();                            // W1t0 resident; buf1 free

    // stage W1 tile1 -> buf1 NOW: DMA flies under the whole epilogue-1 VALU phase
    #pragma unroll
    for (int c = 0; c < 2; ++c)
        cp16(W1T + 8192 + c * 4096 + tid * 8, &Blds[1][c * 4096 + tid * 8]);

    // ---- Epilogue 1: +bias, ELU -> packed bf16 H in private padded HL ----
    // Lane (q,ln) holds edge=ln, n=16nt+4q+{0..3}: 2 cvt_pk + 1 ds_write_b64.
    // Row stride 136 shorts: banks rotate by 4 per row -> b64 writes 2-way
    // (free) and b128 reads conflict-free minimum.
    short* Hw = &HL[wave * 2176];
    short8 a2[2][4];
    #pragma unroll
    for (int mt = 0; mt < 2; ++mt) {
        #pragma unroll
        for (int nt = 0; nt < 8; ++nt) {
            float4v bq = *(const float4v*)(bbi + nt * 16 + q * 4);
            float4v v = acc[mt][nt];
            float y0 = v[0] + bq[0], y1 = v[1] + bq[1];
            float y2 = v[2] + bq[2], y3 = v[3] + bq[3];
            float x0 = y0 > 0.f ? y0 : (__expf(y0) - 1.f);
            float x1 = y1 > 0.f ? y1 : (__expf(y1) - 1.f);
            float x2 = y2 > 0.f ? y2 : (__expf(y2) - 1.f);
            float x3 = y3 > 0.f ? y3 : (__expf(y3) - 1.f);
            *(int2v*)(Hw + ln * 136 + (4 * nt + q) * 4) =
                (int2v){ (int)cvtpk(x0, x1), (int)cvtpk(x2, x3) };
        }
        // same-wave LDS RAW; compiler inserts lgkmcnt wait
        #pragma unroll
        for (int ks = 0; ks < 4; ++ks)
            a2[mt][ks] = *(const short8*)(Hw + ln * 136 + (8 * ks + 2 * q) * 4);
    }

    // acc zero-init for layer 2 (b1 bias added in epilogue 2)
    #pragma unroll
    for (int nt = 0; nt < 8; ++nt) {
        acc[0][nt] = (float4v){0.f, 0.f, 0.f, 0.f};
        acc[1][nt] = (float4v){0.f, 0.f, 0.f, 0.f};
    }

#define L2_TILE(KT) do { \
    if (KT == 1) __syncthreads(); \
    __builtin_amdgcn_s_setprio(1); \
    _Pragma("unroll") \
    for (int ks2 = 0; ks2 < 2; ++ks2) { \
        int ka = (ks2 * 32 + q * 8) ^ swz; \
        _Pragma("unroll") \
        for (int nt = 0; nt < 8; ++nt) { \
            short8 bf = *(const short8*)&Blds[KT][(nt * 16 + ln) * 64 + ka]; \
            acc[0][nt] = __builtin_amdgcn_mfma_f32_16x16x32_bf16(bf, a2[0][KT * 2 + ks2], acc[0][nt], 0, 0, 0); \
            acc[1][nt] = __builtin_amdgcn_mfma_f32_16x16x32_bf16(bf, a2[1][KT * 2 + ks2], acc[1][nt], 0, 0, 0); \
        } \
    } \
    __builtin_amdgcn_s_setprio(0); \
    } while (0)

    // ---- Layer 2: K=128, 2 tiles ----
    L2_TILE(0);                                 // buf0 (covered by the post-L1 barrier)
    L2_TILE(1);                                 // barrier: W1t1 resident in buf1

    // ---- Epilogue 2: +b1, ELU, dot W2 (in-lane), 2-shfl reduce, sigmoid ----
    const float b2s = b2v[0];
    #pragma unroll
    for (int mt = 0; mt < 2; ++mt) {
        float s = 0.f;
        #pragma unroll
        for (int nt = 0; nt < 8; ++nt) {
            float4v b1q = *(const float4v*)(b1v + nt * 16 + q * 4);
            float4v w  = *(const float4v*)(W2v + nt * 16 + q * 4);
            float4v v = acc[mt][nt];
            float x;
            x = v[0] + b1q[0]; x = x > 0.f ? x : (__expf(x) - 1.f); s += x * w[0];
            x = v[1] + b1q[1]; x = x > 0.f ? x : (__expf(x) - 1.f); s += x * w[1];
            x = v[2] + b1q[2]; x = x > 0.f ? x : (__expf(x) - 1.f); s += x * w[2];
            x = v[3] + b1q[3]; x = x > 0.f ? x : (__expf(x) - 1.f); s += x * w[3];
        }
        s += __shfl_xor(s, 16);
        s += __shfl_xor(s, 32);
        if (q == mt) {
            int e = e0 + wave * 32 + mt * 16 + ln;
            if (e < E_EDGES) {
                float z = s + b2s;
                out[type * E_EDGES + e] = 1.f / (1.f + __expf(-z));
            }
        }
    }
#undef GATHER
#undef L1_TILE
#undef L2_TILE
}

extern "C" void kernel_launch(void* const* d_in, const int* in_sizes, int n_in,
                              void* d_out, int out_size, void* d_ws, size_t ws_size,
                              hipStream_t stream) {
    const float* user_emb = (const float*)d_in[0];
    const float* item_emb = (const float*)d_in[1];
    const int*   ei_ui    = (const int*)d_in[2];
    const int*   ei_iu    = (const int*)d_in[3];
    const float* W_bi_ui  = (const float*)d_in[4];
    const float* b_bi_ui  = (const float*)d_in[5];
    const float* W1_ui    = (const float*)d_in[6];
    const float* b1_ui    = (const float*)d_in[7];
    const float* W2_ui    = (const float*)d_in[8];
    const float* b2_ui    = (const float*)d_in[9];
    const float* W_bi_iu  = (const float*)d_in[10];
    const float* b_bi_iu  = (const float*)d_in[11];
    const float* W1_iu    = (const float*)d_in[12];
    const float* b1_iu    = (const float*)d_in[13];
    const float* W2_iu    = (const float*)d_in[14];
    const float* b2_iu    = (const float*)d_in[15];
    short* ws  = (short*)d_ws;
    short* tab = ws + 98304;
    float* out = (float*)d_out;

    const size_t need = 98304u * 2u + (size_t)2 * TAB_ELEMS * 2u;  // 51.4 MB

    hipLaunchKernelGGL(prep_all, dim3(1036, 2), dim3(256), 0, stream,
                       user_emb, item_emb, W_bi_ui, W1_ui, W_bi_iu, W1_iu, ws);
    if (ws_size >= need) {
        edge_decoder<true><<<dim3(NBLK, 2), dim3(512), 0, stream>>>(
            user_emb, item_emb, ei_ui, ei_iu,
            b_bi_ui, b1_ui, W2_ui, b2_ui,
            b_bi_iu, b1_iu, W2_iu, b2_iu,
            ws, tab, out);
    } else {
        edge_decoder<false><<<dim3(NBLK, 2), dim3(512), 0, stream>>>(
            user_emb, item_emb, ei_ui, ei_iu,
            b_bi_ui, b1_ui, W2_ui, b2_ui,
            b_bi_iu, b1_iu, W2_iu, b2_iu,
            ws, tab, out);
    }
}

// Round 12
// 231.234 us; speedup vs baseline: 1.0768x; 1.0768x over previous
//
#include <hip/hip_runtime.h>

typedef __attribute__((ext_vector_type(8))) short short8;
typedef __attribute__((ext_vector_type(4))) float float4v;
typedef __attribute__((ext_vector_type(4))) int int4v;
typedef __attribute__((ext_vector_type(2))) int int2v;

#define E_EDGES 300000
#define EPB 256                                 // edges per block (32 per wave, 8 waves)
#define NBLK ((E_EDGES + EPB - 1) / EPB)        // 1172 blocks per edge type
#define TAB_ELEMS 12800000                      // 100000 nodes x 128 feats

__device__ __forceinline__ short f2bf(float f) {
    unsigned u = __float_as_uint(f);
    return (short)((u + 0x7FFFu + ((u >> 16) & 1u)) >> 16);
}
__device__ __forceinline__ unsigned pk_bf16(float a, float b) {
    unsigned ua = __float_as_uint(a), ub = __float_as_uint(b);
    ua += 0x7FFFu + ((ua >> 16) & 1u);
    ub += 0x7FFFu + ((ub >> 16) & 1u);
    return __builtin_amdgcn_perm(ub, ua, 0x07060302);
}
// HW RNE pack of two f32 -> one u32 of 2 bf16 (lo = a, hi = b).
__device__ __forceinline__ unsigned cvtpk(float a, float b) {
    unsigned r;
    __asm__("v_cvt_pk_bf16_f32 %0, %1, %2" : "=v"(r) : "v"(a), "v"(b));
    return r;
}
__device__ __forceinline__ void cp16(const void* g, void* l) {
    __builtin_amdgcn_global_load_lds(
        (const __attribute__((address_space(1))) unsigned int*)g,
        (__attribute__((address_space(3))) unsigned int*)l, 16, 0, 0);
}

// ws layout (shorts):
//   [0..98304)            weight tiles [n][k] in 64-k tiles, chunk-XOR swizzled
//   [98304..+12.8M)       user_emb bf16
//   [..+25.6M)            item_emb bf16
__global__ void prep_all(const float* __restrict__ ue, const float* __restrict__ ie,
                         const float* __restrict__ Wbi_ui, const float* __restrict__ W1_ui,
                         const float* __restrict__ Wbi_iu, const float* __restrict__ W1_iu,
                         short* __restrict__ ws) {
    __shared__ short tr[64 * 68];
    const int t = blockIdx.y;
    const int tid = threadIdx.x;
    if (blockIdx.x < 1024) {                    // ---- streaming table conversion ----
        const float* src = t ? ie : ue;
        short* dst = ws + 98304 + (size_t)t * TAB_ELEMS;
        const int stride = 1024 * 256;
        for (int g = blockIdx.x * 256 + tid; g < TAB_ELEMS / 8; g += stride) {
            const float* p = src + (size_t)g * 8;
            float4v v0 = ((const float4v*)p)[0];
            float4v v1 = ((const float4v*)p)[1];
            int4v w = { (int)pk_bf16(v0[0], v0[1]), (int)pk_bf16(v0[2], v0[3]),
                        (int)pk_bf16(v1[0], v1[1]), (int)pk_bf16(v1[2], v1[3]) };
            *(int4v*)(dst + (size_t)g * 8) = w;
        }
        return;
    }
    // ---- weight transpose + swizzle (12 tiles per type) ----
    const int m = blockIdx.x - 1024;            // 0..11
    const float* W; int k0, n0, obase;
    if (m < 8) {                                // Wbi (K=256, N=128)
        int kt = m >> 1, nh = m & 1;
        W = t ? Wbi_iu : Wbi_ui; k0 = kt * 64; n0 = nh * 64;
        obase = t * 32768 + kt * 8192;
    } else {                                    // W1 (K=128, N=128)
        int mm = m - 8; int kt = mm >> 1, nh = mm & 1;
        W = t ? W1_iu : W1_ui; k0 = kt * 64; n0 = nh * 64;
        obase = 65536 + t * 16384 + kt * 8192;
    }
    for (int it = 0; it < 16; ++it) {
        int flat = it * 256 + tid;
        int kk = flat >> 6, nn = flat & 63;
        tr[nn * 68 + kk] = f2bf(W[(size_t)(k0 + kk) * 128 + n0 + nn]);
    }
    __syncthreads();
    for (int it = 0; it < 16; ++it) {
        int flat = it * 256 + tid;
        int nn = flat >> 6, kk = flat & 63;
        int n = n0 + nn;
        ws[obase + n * 64 + (kk ^ ((n & 7) << 3))] = tr[nn * 68 + kk];
    }
}

// Round-10 verified cell (session best: 94 us decoder, no spill, padded-H)
// with ONE liveness-neutral reorder: epilogue-1 (pure per-wave VALU + private
// HL; touches no shared buffers) moved BEFORE the post-L1 barrier, so the
// W1-tile0 DMA drains under ~800 cyc of epilogue VALU instead of sitting
// exposed right after tile-3's MFMAs. W1-tile1 staging moves after the
// combined barrier and flies under acc-init + L2-tile-0.
// (Round-11's counted-vmcnt asm barriers regressed 22% — compiler-invisible
// barrier semantics made scheduling worse; reverted.)
template<bool BF16G>
__launch_bounds__(512, 4)
__global__ void edge_decoder(
    const float* __restrict__ user_emb, const float* __restrict__ item_emb,
    const int* __restrict__ ei_ui, const int* __restrict__ ei_iu,
    const float* __restrict__ b_bi_ui, const float* __restrict__ b1_ui,
    const float* __restrict__ W2_ui, const float* __restrict__ b2_ui,
    const float* __restrict__ b_bi_iu, const float* __restrict__ b1_iu,
    const float* __restrict__ W2_iu, const float* __restrict__ b2_iu,
    const short* __restrict__ ws, const short* __restrict__ tab,
    float* __restrict__ out)
{
    __shared__ short Blds[2][128 * 64];         // 32 KiB weight double buffer
    __shared__ short HL[8 * 2176];              // 34 KiB H (16 rows x 136 per wave)

    const int type = blockIdx.y;
    const int tid = threadIdx.x;
    const int wave = tid >> 6, lane = tid & 63;
    const int q = lane >> 4, ln = lane & 15;
    const int e0 = blockIdx.x * EPB;

    const int*   ei   = type ? ei_iu : ei_ui;
    const float* bbi  = type ? b_bi_iu : b_bi_ui;
    const float* b1v  = type ? b1_iu : b1_ui;
    const float* W2v  = type ? W2_iu : W2_ui;
    const float* b2v  = type ? b2_iu : b2_ui;
    const short* WbiT = ws + type * 32768;
    const short* W1T  = ws + 65536 + type * 16384;

    // DMA weight tile 0 -> buf0 immediately (overlaps index load + gather)
    #pragma unroll
    for (int c = 0; c < 2; ++c)
        cp16(WbiT + c * 4096 + tid * 8, &Blds[0][c * 4096 + tid * 8]);

    // two edges per lane (M-tiles mt=0,1); edge-in-tile = ln
    int si[2], di[2];
    #pragma unroll
    for (int mt = 0; mt < 2; ++mt) {
        int erow = e0 + wave * 32 + mt * 16 + ln;
        int safe = (erow < E_EDGES) ? erow : 0;
        si[mt] = ei[safe];
        di[mt] = ei[E_EDGES + safe];
    }

    const short* sp[2]; const short* dp[2];     // bf16-table path
    const float* spf[2]; const float* dpf[2];   // fp32 fallback path
    if (BF16G) {
        #pragma unroll
        for (int mt = 0; mt < 2; ++mt) {
            sp[mt] = tab + (size_t)(type ? TAB_ELEMS : 0) + (size_t)si[mt] * 128 + q * 8;
            dp[mt] = tab + (size_t)(type ? 0 : TAB_ELEMS) + (size_t)di[mt] * 128 + q * 8;
        }
    } else {
        const float* srcT = type ? item_emb : user_emb;
        const float* dstT = type ? user_emb : item_emb;
        #pragma unroll
        for (int mt = 0; mt < 2; ++mt) {
            spf[mt] = srcT + (size_t)si[mt] * 128 + q * 8;
            dpf[mt] = dstT + (size_t)di[mt] * 128 + q * 8;
        }
    }

    short8 aA[2][2], aB[2][2];                  // ping-pong per-tile edge fragments

#define GATHER(BUF, HALF, OFF) do { \
    _Pragma("unroll") \
    for (int mt = 0; mt < 2; ++mt) { \
        _Pragma("unroll") \
        for (int k2 = 0; k2 < 2; ++k2) { \
            if (BF16G) { \
                BUF[mt][k2] = *(const short8*)((HALF ? dp[mt] : sp[mt]) + OFF + k2 * 32); \
            } else { \
                const float* p = (HALF ? dpf[mt] : spf[mt]) + OFF + k2 * 32; \
                float4v v0 = ((const float4v*)p)[0]; \
                float4v v1 = ((const float4v*)p)[1]; \
                int4v w = { (int)cvtpk(v0[0], v0[1]), (int)cvtpk(v0[2], v0[3]), \
                            (int)cvtpk(v1[0], v1[1]), (int)cvtpk(v1[2], v1[3]) }; \
                BUF[mt][k2] = *(short8*)&w; \
            } \
        } \
    } } while (0)

    GATHER(aA, 0, 0);                           // tile 0: src[0:64)
    GATHER(aB, 0, 64);                          // tile 1: src[64:128)

    // acc init = bias; swapped D => rows are n = 16nt+4q+r -> one float4 load
    float4v acc[2][8];
    #pragma unroll
    for (int nt = 0; nt < 8; ++nt) {
        acc[0][nt] = *(const float4v*)(bbi + nt * 16 + q * 4);
        acc[1][nt] = acc[0][nt];
    }

    const int swz = (ln & 7) << 3;              // weight-tile 16B-chunk xor

// One layer-1 K-tile, SWAPPED operands: mfma(W_frag, edge_frag, acc).
#define L1_TILE(KT, ABUF) do { \
    __syncthreads(); \
    const short* nxt = (KT < 3) ? (WbiT + (KT + 1) * 8192) : W1T; \
    _Pragma("unroll") \
    for (int c = 0; c < 2; ++c) \
        cp16(nxt + c * 4096 + tid * 8, &Blds[(KT + 1) & 1][c * 4096 + tid * 8]); \
    __builtin_amdgcn_s_setprio(1); \
    _Pragma("unroll") \
    for (int ks2 = 0; ks2 < 2; ++ks2) { \
        int ka = (ks2 * 32 + q * 8) ^ swz; \
        _Pragma("unroll") \
        for (int nt = 0; nt < 8; ++nt) { \
            short8 bf = *(const short8*)&Blds[KT & 1][(nt * 16 + ln) * 64 + ka]; \
            acc[0][nt] = __builtin_amdgcn_mfma_f32_16x16x32_bf16(bf, ABUF[0][ks2], acc[0][nt], 0, 0, 0); \
            acc[1][nt] = __builtin_amdgcn_mfma_f32_16x16x32_bf16(bf, ABUF[1][ks2], acc[1][nt], 0, 0, 0); \
        } \
    } \
    __builtin_amdgcn_s_setprio(0); \
    } while (0)

    // ---- Layer 1: K=256 concat [src|dst], 4 tiles of 64-K ----
    L1_TILE(0, aA);
    GATHER(aA, 1, 0);                           // tile 2: dst[0:64)
    L1_TILE(1, aB);
    GATHER(aB, 1, 64);                          // tile 3: dst[64:128)
    L1_TILE(2, aA);
    L1_TILE(3, aB);                             // stages W1 tile0 -> buf0

    // ---- Epilogue 1 (BEFORE the barrier: private HL + VALU only) ----
    // W1t0 DMA drains under this ~800-cyc phase instead of sitting exposed.
    // Lane (q,ln) holds edge=ln, n=16nt+4q+{0..3}: 2 cvt_pk + 1 ds_write_b64.
    // Row stride 136 shorts: banks rotate by 4 per row -> b64 writes 2-way
    // (free) and b128 reads conflict-free minimum.
    short* Hw = &HL[wave * 2176];
    short8 a2[2][4];
    #pragma unroll
    for (int mt = 0; mt < 2; ++mt) {
        #pragma unroll
        for (int nt = 0; nt < 8; ++nt) {
            float4v v = acc[mt][nt];
            float x0 = v[0] > 0.f ? v[0] : (__expf(v[0]) - 1.f);
            float x1 = v[1] > 0.f ? v[1] : (__expf(v[1]) - 1.f);
            float x2 = v[2] > 0.f ? v[2] : (__expf(v[2]) - 1.f);
            float x3 = v[3] > 0.f ? v[3] : (__expf(v[3]) - 1.f);
            *(int2v*)(Hw + ln * 136 + (4 * nt + q) * 4) =
                (int2v){ (int)cvtpk(x0, x1), (int)cvtpk(x2, x3) };
        }
        // same-wave LDS RAW; compiler inserts lgkmcnt wait
        #pragma unroll
        for (int ks = 0; ks < 4; ++ks)
            a2[mt][ks] = *(const short8*)(Hw + ln * 136 + (8 * ks + 2 * q) * 4);
    }

    __syncthreads();                            // combined: W1t0 resident (drain
                                                // hidden under epi-1) + buf1 free

    // stage W1 tile1 -> buf1; flies under acc-init + L2 tile 0
    #pragma unroll
    for (int c = 0; c < 2; ++c)
        cp16(W1T + 8192 + c * 4096 + tid * 8, &Blds[1][c * 4096 + tid * 8]);

    #pragma unroll
    for (int nt = 0; nt < 8; ++nt) {
        acc[0][nt] = *(const float4v*)(b1v + nt * 16 + q * 4);
        acc[1][nt] = acc[0][nt];
    }

#define L2_TILE(KT) do { \
    if (KT == 1) __syncthreads(); \
    __builtin_amdgcn_s_setprio(1); \
    _Pragma("unroll") \
    for (int ks2 = 0; ks2 < 2; ++ks2) { \
        int ka = (ks2 * 32 + q * 8) ^ swz; \
        _Pragma("unroll") \
        for (int nt = 0; nt < 8; ++nt) { \
            short8 bf = *(const short8*)&Blds[KT][(nt * 16 + ln) * 64 + ka]; \
            acc[0][nt] = __builtin_amdgcn_mfma_f32_16x16x32_bf16(bf, a2[0][KT * 2 + ks2], acc[0][nt], 0, 0, 0); \
            acc[1][nt] = __builtin_amdgcn_mfma_f32_16x16x32_bf16(bf, a2[1][KT * 2 + ks2], acc[1][nt], 0, 0, 0); \
        } \
    } \
    __builtin_amdgcn_s_setprio(0); \
    } while (0)

    // ---- Layer 2: K=128, 2 tiles ----
    L2_TILE(0);                                 // buf0 (guarded by combined barrier)
    L2_TILE(1);                                 // entry barrier: W1t1 resident in buf1

    // ---- Epilogue 2: ELU, dot W2 (in-lane), 2-shfl reduce, sigmoid, store ----
    float4v w2q[8];
    #pragma unroll
    for (int nt = 0; nt < 8; ++nt)
        w2q[nt] = *(const float4v*)(W2v + nt * 16 + q * 4);
    const float b2s = b2v[0];

    #pragma unroll
    for (int mt = 0; mt < 2; ++mt) {
        float s = 0.f;
        #pragma unroll
        for (int nt = 0; nt < 8; ++nt) {
            float4v v = acc[mt][nt];
            float4v w = w2q[nt];
            float x;
            x = v[0]; x = x > 0.f ? x : (__expf(x) - 1.f); s += x * w[0];
            x = v[1]; x = x > 0.f ? x : (__expf(x) - 1.f); s += x * w[1];
            x = v[2]; x = x > 0.f ? x : (__expf(x) - 1.f); s += x * w[2];
            x = v[3]; x = x > 0.f ? x : (__expf(x) - 1.f); s += x * w[3];
        }
        s += __shfl_xor(s, 16);
        s += __shfl_xor(s, 32);
        if (q == mt) {
            int e = e0 + wave * 32 + mt * 16 + ln;
            if (e < E_EDGES) {
                float z = s + b2s;
                out[type * E_EDGES + e] = 1.f / (1.f + __expf(-z));
            }
        }
    }
#undef GATHER
#undef L1_TILE
#undef L2_TILE
}

extern "C" void kernel_launch(void* const* d_in, const int* in_sizes, int n_in,
                              void* d_out, int out_size, void* d_ws, size_t ws_size,
                              hipStream_t stream) {
    const float* user_emb = (const float*)d_in[0];
    const float* item_emb = (const float*)d_in[1];
    const int*   ei_ui    = (const int*)d_in[2];
    const int*   ei_iu    = (const int*)d_in[3];
    const float* W_bi_ui  = (const float*)d_in[4];
    const float* b_bi_ui  = (const float*)d_in[5];
    const float* W1_ui    = (const float*)d_in[6];
    const float* b1_ui    = (const float*)d_in[7];
    const float* W2_ui    = (const float*)d_in[8];
    const float* b2_ui    = (const float*)d_in[9];
    const float* W_bi_iu  = (const float*)d_in[10];
    const float* b_bi_iu  = (const float*)d_in[11];
    const float* W1_iu    = (const float*)d_in[12];
    const float* b1_iu    = (const float*)d_in[13];
    const float* W2_iu    = (const float*)d_in[14];
    const float* b2_iu    = (const float*)d_in[15];
    short* ws  = (short*)d_ws;
    short* tab = ws + 98304;
    float* out = (float*)d_out;

    const size_t need = 98304u * 2u + (size_t)2 * TAB_ELEMS * 2u;  // 51.4 MB

    hipLaunchKernelGGL(prep_all, dim3(1036, 2), dim3(256), 0, stream,
                       user_emb, item_emb, W_bi_ui, W1_ui, W_bi_iu, W1_iu, ws);
    if (ws_size >= need) {
        edge_decoder<true><<<dim3(NBLK, 2), dim3(512), 0, stream>>>(
            user_emb, item_emb, ei_ui, ei_iu,
            b_bi_ui, b1_ui, W2_ui, b2_ui,
            b_bi_iu, b1_iu, W2_iu, b2_iu,
            ws, tab, out);
    } else {
        edge_decoder<false><<<dim3(NBLK, 2), dim3(512), 0, stream>>>(
            user_emb, item_emb, ei_ui, ei_iu,
            b_bi_ui, b1_ui, W2_ui, b2_ui,
            b_bi_iu, b1_iu, W2_iu, b2_iu,
            ws, tab, out);
    }
}